// Round 11
// baseline (415.823 us; speedup 1.0000x reference)
//
#include <hip/hip_runtime.h>
#include <hip/hip_fp16.h>

#define S 1024
#define B 8
#define NH 8
#define DH 32
#define HID 256
#define SCALEF 0.17677669529663687f

typedef __attribute__((ext_vector_type(8))) _Float16 f16x8;
typedef __attribute__((ext_vector_type(4))) _Float16 f16x4;
typedef __attribute__((ext_vector_type(4))) float f32x4;
#define MFMAH(a, b, c) __builtin_amdgcn_mfma_f32_16x16x32_f16(a, b, c, 0, 0, 0)

// ---- LDS layout (halfs), 17920 halfs = 35 KB (single-f16 K, dbuf) ----
#define OFF_K   0        // 2 buf x 32 x 40 (f16 K)
#define OFF_VT  2560     // 2 buf x 32(d) x 40, col-XOR-swizzled
#define OFF_RL  5120     // ring 8 slots x 16 x 40
#define OFF_RH  10240
#define OFF_P   15360    // 4 waves x 16 x 40
#define LDS_HF  17920

#define C_E2  0.51006978f      // 2*SCALE/ln2
#define C_PWA 14.42695041f     // 10/ln2
#define C_PWB -28.85390082f    // -20/ln2

// ---- control block (ints), lives at d_ws + 128MiB ----
// [0..15] stripe flags  [16] row ticket  [17] leftover count  [18..1041] leftover rows
#define CTRL_INTS 1042

__device__ __forceinline__ void cvtf16_4(const float4 x, _Float16* d) {
  f16x4 h;
  h.x = (_Float16)x.x; h.y = (_Float16)x.y; h.z = (_Float16)x.z; h.w = (_Float16)x.w;
  *(f16x4*)d = h;
}

// =================== shared probs-row routine (256 threads) ===================
__device__ __forceinline__ void probs_row_256(
    int i, const __half* __restrict__ sws, const int* __restrict__ mask,
    float* __restrict__ probs, _Float16* ebuf, unsigned char* mb,
    float* psum, float* binv) {
  const int t = threadIdx.x;
  {
    const int4* m4 = (const int4*)(mask + (size_t)i * 8192);
#pragma unroll
    for (int uu = 0; uu < 8; ++uu) {
      int idx = t + (uu << 8);
      int4 mv = m4[idx];
      int jj = idx >> 1, b0 = (idx & 1) << 2;
      mb[jj * 9 + b0 + 0] = (unsigned char)(mv.x != 0);
      mb[jj * 9 + b0 + 1] = (unsigned char)(mv.y != 0);
      mb[jj * 9 + b0 + 2] = (unsigned char)(mv.z != 0);
      mb[jj * 9 + b0 + 3] = (unsigned char)(mv.w != 0);
    }
  }
  __syncthreads();
  const int b = t >> 5, g32 = t & 31;
  float s = 0.f;
#pragma unroll
  for (int rep = 0; rep < 8; ++rep) {
    const int j4 = (g32 + (rep << 5)) << 2;
    float a0 = 1.f, a1 = 1.f, a2 = 1.f, a3 = 1.f;
#pragma unroll
    for (int n = 0; n < 8; ++n) {
      f16x4 pv = *(const f16x4*)(sws + (((size_t)i * 8 + b) * 8 + n) * 1024 + j4);
      a0 *= (float)pv.x; a1 *= (float)pv.y; a2 *= (float)pv.z; a3 *= (float)pv.w;
    }
    float e0 = mb[(j4 + 0) * 9 + b] ? 0.f
             : __builtin_amdgcn_exp2f(0.125f * __builtin_amdgcn_logf(a0));
    float e1 = mb[(j4 + 1) * 9 + b] ? 0.f
             : __builtin_amdgcn_exp2f(0.125f * __builtin_amdgcn_logf(a1));
    float e2 = mb[(j4 + 2) * 9 + b] ? 0.f
             : __builtin_amdgcn_exp2f(0.125f * __builtin_amdgcn_logf(a2));
    float e3 = mb[(j4 + 3) * 9 + b] ? 0.f
             : __builtin_amdgcn_exp2f(0.125f * __builtin_amdgcn_logf(a3));
    f16x4 ev;
    ev.x = (_Float16)e0; ev.y = (_Float16)e1; ev.z = (_Float16)e2; ev.w = (_Float16)e3;
    *(f16x4*)&ebuf[b * 1032 + j4] = ev;
    s += ((float)ev.x + (float)ev.y) + ((float)ev.z + (float)ev.w);
  }
#pragma unroll
  for (int off = 16; off > 0; off >>= 1) s += __shfl_xor(s, off, 64);
  if (g32 == 0) psum[b] = s;
  __syncthreads();
  if (t < 8) binv[t] = 1.0f / psum[t];
  __syncthreads();
#pragma unroll
  for (int uu = 0; uu < 8; ++uu) {
    int f0 = (t << 2) + (uu << 10);
    float4 o;
    o.x = (float)ebuf[((f0 + 0) & 7) * 1032 + ((f0 + 0) >> 3)] * binv[(f0 + 0) & 7];
    o.y = (float)ebuf[((f0 + 1) & 7) * 1032 + ((f0 + 1) >> 3)] * binv[(f0 + 1) & 7];
    o.z = (float)ebuf[((f0 + 2) & 7) * 1032 + ((f0 + 2) >> 3)] * binv[(f0 + 2) & 7];
    o.w = (float)ebuf[((f0 + 3) & 7) * 1032 + ((f0 + 3) >> 3)] * binv[(f0 + 3) & 7];
    *(float4*)(probs + (size_t)i * 8192 + f0) = o;
  }
}

// =================== ctrl init ===================
__global__ __launch_bounds__(1024)
void relattn_init_ctrl(int* __restrict__ ctrl) {
  int t = threadIdx.x + blockIdx.x * 1024;
  if (t < CTRL_INTS) ctrl[t] = 0;
}

// =================== fused producer/consumer kernel (1024 blocks x 1 unit) ===================
// unit = blockIdx.x, stripe-contiguous (it = u>>6). Producer phase identical in
// shape/residency to the proven R9 mfma kernel (4 blocks/CU). After its unit,
// each block claims probs rows whose stripe flag shows all 64 producers done.
// Bounded spin; timeouts -> leftover list drained by trailing cleanup kernel.
__global__ __launch_bounds__(256)
void relattn_fused_86028194939537(const float* __restrict__ q, const float* __restrict__ k,
                                  const float* __restrict__ v, const float* __restrict__ r,
                                  const float* __restrict__ bu, const float* __restrict__ bv,
                                  const int* __restrict__ mask, float* __restrict__ out,
                                  float* __restrict__ probs, __half* __restrict__ sws,
                                  int* __restrict__ ctrl) {
  __shared__ _Float16 sm[LDS_HF];
  __shared__ float psum[8];
  __shared__ float binv[8];
  __shared__ int smrow;
  __shared__ int smok;
  const int t = threadIdx.x;
  const int lane = t & 63, w = t >> 6;
  const int quad = lane >> 4, jn = lane & 15;
  const int colq = quad << 3;
  const int jstage = t >> 3, dstage = (t & 7) << 2;
  const int jsw = jstage ^ ((t & 3) << 3);
  const int vcolsw = colq ^ (((jn >> 2) & 3) << 3);

  int* flags = ctrl;
  int* rowctr = ctrl + 16;
  int* lcnt = ctrl + 17;
  int* lrows = ctrl + 18;

  // ---------------- producer phase: ONE unit ----------------
  {
    const int u = (int)blockIdx.x;
    const int it = u >> 6, n = (u >> 3) & 7, b = u & 7;
    const int i0 = it << 6, iw0 = i0 + (w << 4);
    const int i16 = i0 >> 4;
    const int jtL_last = (i0 + 63) >> 5;
    const bool proH = (i0 <= 125);

    f16x8 qu_h, qu_l, qv_h, qv_l, qn_h, qn_l;
    {
      const float* bup = bu + n * DH + colq;
      const float* bvp = bv + n * DH + colq;
      const float* qp = q + (size_t)(iw0 + jn) * 2048 + b * HID + n * DH + colq;
      int r1 = iw0 + 1 + jn; if (r1 > S - 1) r1 = S - 1;
      const float* qp1 = q + (size_t)r1 * 2048 + b * HID + n * DH + colq;
#pragma unroll
      for (int e = 0; e < 8; ++e) {
        float xu = (qp[e] + bup[e]) * C_E2;
        float xv = (qp[e] + bvp[e]) * C_E2;
        float xn = (qp1[e] + bvp[e]) * C_E2;
        _Float16 h;
        h = (_Float16)xu; qu_h[e] = h; qu_l[e] = (_Float16)(xu - (float)h);
        h = (_Float16)xv; qv_h[e] = h; qv_l[e] = (_Float16)(xv - (float)h);
        h = (_Float16)xn; qn_h[e] = h; qn_l[e] = (_Float16)(xn - (float)h);
      }
    }
    f16x8 ones1;
#pragma unroll
    for (int e = 0; e < 8; ++e) ones1[e] = (_Float16)1.0f;

    __half* swsp = sws + (((size_t)(iw0 + jn) * 8 + b) * 8 + n) * 1024 + colq;

    f32x4 out0 = {0.f, 0.f, 0.f, 0.f}, out1 = {0.f, 0.f, 0.f, 0.f};
    f32x4 out_sum = {0.f, 0.f, 0.f, 0.f};

    {
      const size_t g = (size_t)jstage * 2048 + b * HID + n * DH + dstage;
      float4 kx = *(const float4*)(k + g);
      float4 vx = *(const float4*)(v + g);
      cvtf16_4(kx, &sm[OFF_K + jstage * 40 + dstage]);
      sm[OFF_VT + (dstage + 0) * 40 + jsw] = (_Float16)vx.x;
      sm[OFF_VT + (dstage + 1) * 40 + jsw] = (_Float16)vx.y;
      sm[OFF_VT + (dstage + 2) * 40 + jsw] = (_Float16)vx.z;
      sm[OFF_VT + (dstage + 3) * 40 + jsw] = (_Float16)vx.w;
    }
#pragma unroll
    for (int p = 0; p < 3; ++p) {
      int ti = 2 * p + (t >> 7), row = (t >> 3) & 15, d4 = (t & 7) << 2;
      {
        int kL = 60 - i16 + ti;
        int tg = (kL << 4) + row; tg = tg < 0 ? 0 : (tg > S - 1 ? S - 1 : tg);
        float4 rv = *(const float4*)(r + (size_t)tg * HID + n * DH + d4);
        int sl = (kL + 72) & 7;
        cvtf16_4(rv, &sm[OFF_RL + (sl * 16 + row) * 40 + d4]);
      }
      if (proH) {
        int kH = -i16 - 3 + ti;
        int tg = (kH << 4) - 17 + row; tg = tg < 0 ? 0 : (tg > S - 1 ? S - 1 : tg);
        float4 rv = *(const float4*)(r + (size_t)tg * HID + n * DH + d4);
        int sl = (kH + 72) & 7;
        cvtf16_4(rv, &sm[OFF_RH + (sl * 16 + row) * 40 + d4]);
      }
    }

    for (int jt = 0; jt < 32; ++jt) {
      const int j0 = jt << 5;
      __syncthreads();

      const bool doKV = (jt < 31);
      const bool doRL = (jt <= jtL_last);
      const bool doRH = (32 * jt >= i0 - 125);
      float4 kx, vx, rlv, rhv;
      int slL = 0, slH = 0;
      {
        if (doKV) {
          const size_t g = (size_t)(j0 + 32 + jstage) * 2048 + b * HID + n * DH + dstage;
          kx = *(const float4*)(k + g);
          vx = *(const float4*)(v + g);
        }
        const int ti = t >> 7, row = (t >> 3) & 15, d4r = (t & 7) << 2;
        if (doRL) {
          int kL = 66 + 2 * jt - i16 + ti;
          int tg = (kL << 4) + row; tg = tg < 0 ? 0 : (tg > S - 1 ? S - 1 : tg);
          rlv = *(const float4*)(r + (size_t)tg * HID + n * DH + d4r);
          slL = (kL + 72) & 7;
        }
        if (doRH) {
          int kH = 2 * jt - i16 + 3 + ti;
          int tg = (kH << 4) - 17 + row; tg = tg < 0 ? 0 : (tg > S - 1 ? S - 1 : tg);
          rhv = *(const float4*)(r + (size_t)tg * HID + n * DH + d4r);
          slH = (kH + 72) & 7;
        }
      }

      const int buf = (jt & 1) * 1280;
      const bool lowA = (j0 <= iw0 + 15);
      const bool highA = (j0 + 29 >= iw0);

      f32x4 ac0 = {0.f, 0.f, 0.f, 0.f}, ac1 = {0.f, 0.f, 0.f, 0.f};
      {
        f16x8 b0 = *(const f16x8*)&sm[OFF_K + buf + jn * 40 + colq];
        f16x8 b1 = *(const f16x8*)&sm[OFF_K + buf + (16 + jn) * 40 + colq];
        ac0 = MFMAH(qu_h, b0, ac0); ac0 = MFMAH(qu_l, b0, ac0);
        ac1 = MFMAH(qu_h, b1, ac1); ac1 = MFMAH(qu_l, b1, ac1);
      }

      f32x4 zl0 = {0.f,0.f,0.f,0.f}, zl1 = {0.f,0.f,0.f,0.f}, zl2 = {0.f,0.f,0.f,0.f};
      f32x4 zh0 = {0.f,0.f,0.f,0.f}, zh1 = {0.f,0.f,0.f,0.f}, zh2 = {0.f,0.f,0.f,0.f};
      if (lowA) {
#pragma unroll
        for (int z = 0; z < 3; ++z) {
          int kL = 63 - i16 - w + 2 * jt + z;
          int sl = (kL + 72) & 7;
          f16x8 rr = *(const f16x8*)&sm[OFF_RL + (sl * 16 + jn) * 40 + colq];
          f32x4 acc = {0.f, 0.f, 0.f, 0.f};
          acc = MFMAH(qv_h, rr, acc); acc = MFMAH(qv_l, rr, acc);
          if (z == 0) zl0 = acc; else if (z == 1) zl1 = acc; else zl2 = acc;
        }
      }
      if (highA) {
#pragma unroll
        for (int z = 0; z < 3; ++z) {
          int kH = 2 * jt - i16 - w + z;
          int sl = (kH + 72) & 7;
          f16x8 rr = *(const f16x8*)&sm[OFF_RH + (sl * 16 + jn) * 40 + colq];
          f32x4 acc = {0.f, 0.f, 0.f, 0.f};
          acc = MFMAH(qn_h, rr, acc); acc = MFMAH(qn_l, rr, acc);
          if (z == 0) zh0 = acc; else if (z == 1) zh1 = acc; else zh2 = acc;
        }
      }

#pragma unroll
      for (int g = 0; g < 4; ++g) {
        const int qr = (quad << 2) + g;
        const int c0 = 15 - qr + jn;
        const int src = (lane & 48) | (c0 & 15);
        const bool pred = (jn >= 15 - qr);
        float lo0 = 0.f, lo1 = 0.f, hv0 = 0.f, hv1 = 0.f;
        if (lowA) {
          float vA = pred ? zl0[g] : zl1[g];
          float vB = pred ? zl1[g] : zl2[g];
          lo0 = __shfl(vA, src, 64);
          lo1 = __shfl(vB, src, 64);
        }
        if (highA) {
          float vA = pred ? zh0[g] : zh1[g];
          float vB = pred ? zh1[g] : zh2[g];
          hv0 = __shfl(vA, src, 64);
          hv1 = __shfl(vB, src, 64);
        }
        const int dj0 = j0 + jn - iw0 - qr;
#pragma unroll
        for (int f = 0; f < 2; ++f) {
          const int dj = dj0 + (f << 4);
          const float bd = (dj <= 0) ? (f ? lo1 : lo0) : ((dj == 1) ? 0.f : (f ? hv1 : hv0));
          const float acv = f ? ac1[g] : ac0[g];
          const float sc = acv + bd;
          const float e2 = __builtin_amdgcn_exp2f(sc);
          const float tq = __builtin_amdgcn_rcpf(e2 + 1.f);
          const float pw = __builtin_amdgcn_exp2f(fmaf(tq, C_PWB, C_PWA));
          sm[OFF_P + w * 640 + qr * 40 + (f << 4) + jn] = (_Float16)pw;
        }
      }

      {
        f16x8 pa = *(const f16x8*)&sm[OFF_P + w * 640 + jn * 40 + colq];
        f16x8 v0 = *(const f16x8*)&sm[OFF_VT + buf + jn * 40 + vcolsw];
        f16x8 v1 = *(const f16x8*)&sm[OFF_VT + buf + (16 + jn) * 40 + vcolsw];
        out0 = MFMAH(pa, v0, out0);
        out1 = MFMAH(pa, v1, out1);
        out_sum = MFMAH(pa, ones1, out_sum);
        *(f16x8*)swsp = pa;
        swsp += 32;
      }

      {
        if (doKV) {
          const int nbuf = ((jt + 1) & 1) * 1280;
          cvtf16_4(kx, &sm[OFF_K + nbuf + jstage * 40 + dstage]);
          sm[OFF_VT + nbuf + (dstage + 0) * 40 + jsw] = (_Float16)vx.x;
          sm[OFF_VT + nbuf + (dstage + 1) * 40 + jsw] = (_Float16)vx.y;
          sm[OFF_VT + nbuf + (dstage + 2) * 40 + jsw] = (_Float16)vx.z;
          sm[OFF_VT + nbuf + (dstage + 3) * 40 + jsw] = (_Float16)vx.w;
        }
        const int row = (t >> 3) & 15, d4r = (t & 7) << 2;
        if (doRL) cvtf16_4(rlv, &sm[OFF_RL + (slL * 16 + row) * 40 + d4r]);
        if (doRH) cvtf16_4(rhv, &sm[OFF_RH + (slH * 16 + row) * 40 + d4r]);
      }
    }

#pragma unroll
    for (int g = 0; g < 4; ++g) {
      const float inv = 1.0f / out_sum[g];
      const int qr = (quad << 2) + g;
      float* op = out + (size_t)(iw0 + qr) * 2048 + b * HID + n * DH;
      op[jn] = out0[g] * inv;
      op[16 + jn] = out1[g] * inv;
    }

    __syncthreads();
    if (t == 0) {
      __threadfence();
      __hip_atomic_fetch_add(&flags[it], 1, __ATOMIC_RELEASE, __HIP_MEMORY_SCOPE_AGENT);
    }
  }

  // ---------------- consumer phase: claim probs rows ----------------
  for (;;) {
    if (t == 0)
      smrow = __hip_atomic_fetch_add(rowctr, 1, __ATOMIC_RELAXED, __HIP_MEMORY_SCOPE_AGENT);
    __syncthreads();
    const int row = smrow;
    if (row >= S) break;
    const int st = row >> 6;
    if (t == 0) {
      int ok = 0;
      for (int sp = 0; sp < 20000; ++sp) {
        if (__hip_atomic_load(&flags[st], __ATOMIC_RELAXED, __HIP_MEMORY_SCOPE_AGENT) >= 64) {
          ok = 1; break;
        }
        __builtin_amdgcn_s_sleep(8);
      }
      if (ok) {
        (void)__hip_atomic_load(&flags[st], __ATOMIC_ACQUIRE, __HIP_MEMORY_SCOPE_AGENT);
      } else {
        int li = __hip_atomic_fetch_add(lcnt, 1, __ATOMIC_RELAXED, __HIP_MEMORY_SCOPE_AGENT);
        lrows[li] = row;
        __threadfence();
      }
      smok = ok;
    }
    __syncthreads();
    if (!smok) continue;
    probs_row_256(row, sws, mask, probs, sm, (unsigned char*)(sm + 8704), psum, binv);
    __syncthreads();
  }
}

// =================== leftover cleanup (runs after fused completes) ===================
__global__ __launch_bounds__(256)
void relattn_cleanup_86028194939537(const __half* __restrict__ sws, const int* __restrict__ mask,
                                    float* __restrict__ probs, const int* __restrict__ ctrl) {
  __shared__ _Float16 ebuf[8 * 1032];
  __shared__ unsigned char mb[9224];
  __shared__ float psum[8];
  __shared__ float binv[8];
  const int cnt = ctrl[17];
  if ((int)blockIdx.x >= cnt) return;
  const int row = ctrl[18 + blockIdx.x];
  probs_row_256(row, sws, mask, probs, ebuf, mb, psum, binv);
}

// =================== tier-b: R9 two-kernel path (proven 247 us) ===================
__global__ __launch_bounds__(256)
void relattn_mfma_86028194939537(const float* __restrict__ q, const float* __restrict__ k,
                                 const float* __restrict__ v, const float* __restrict__ r,
                                 const float* __restrict__ bu, const float* __restrict__ bv,
                                 float* __restrict__ out, __half* __restrict__ sws) {
  __shared__ _Float16 sm[LDS_HF];
  const int t = threadIdx.x;
  const int lane = t & 63, w = t >> 6;
  const int quad = lane >> 4, jn = lane & 15;
  const int bid = blockIdx.x;
  const int b = bid & 7, it = (bid >> 3) & 15, n = bid >> 7;
  const int i0 = it << 6, iw0 = i0 + (w << 4);
  const int colq = quad << 3;
  const int i16 = i0 >> 4;
  const int jstage = t >> 3, dstage = (t & 7) << 2;
  const int jsw = jstage ^ ((t & 3) << 3);
  const int vcolsw = colq ^ (((jn >> 2) & 3) << 3);
  const int jtL_last = (i0 + 63) >> 5;
  const bool proH = (i0 <= 125);

  f16x8 qu_h, qu_l, qv_h, qv_l, qn_h, qn_l;
  {
    const float* bup = bu + n * DH + colq;
    const float* bvp = bv + n * DH + colq;
    const float* qp = q + (size_t)(iw0 + jn) * 2048 + b * HID + n * DH + colq;
    int r1 = iw0 + 1 + jn; if (r1 > S - 1) r1 = S - 1;
    const float* qp1 = q + (size_t)r1 * 2048 + b * HID + n * DH + colq;
#pragma unroll
    for (int e = 0; e < 8; ++e) {
      float xu = (qp[e] + bup[e]) * C_E2;
      float xv = (qp[e] + bvp[e]) * C_E2;
      float xn = (qp1[e] + bvp[e]) * C_E2;
      _Float16 h;
      h = (_Float16)xu; qu_h[e] = h; qu_l[e] = (_Float16)(xu - (float)h);
      h = (_Float16)xv; qv_h[e] = h; qv_l[e] = (_Float16)(xv - (float)h);
      h = (_Float16)xn; qn_h[e] = h; qn_l[e] = (_Float16)(xn - (float)h);
    }
  }
  f16x8 ones1;
#pragma unroll
  for (int e = 0; e < 8; ++e) ones1[e] = (_Float16)1.0f;

  __half* swsp = sws + (((size_t)(iw0 + jn) * 8 + b) * 8 + n) * 1024 + colq;

  f32x4 out0 = {0.f, 0.f, 0.f, 0.f}, out1 = {0.f, 0.f, 0.f, 0.f};
  f32x4 out_sum = {0.f, 0.f, 0.f, 0.f};

  {
    const size_t g = (size_t)jstage * 2048 + b * HID + n * DH + dstage;
    float4 kx = *(const float4*)(k + g);
    float4 vx = *(const float4*)(v + g);
    cvtf16_4(kx, &sm[OFF_K + jstage * 40 + dstage]);
    sm[OFF_VT + (dstage + 0) * 40 + jsw] = (_Float16)vx.x;
    sm[OFF_VT + (dstage + 1) * 40 + jsw] = (_Float16)vx.y;
    sm[OFF_VT + (dstage + 2) * 40 + jsw] = (_Float16)vx.z;
    sm[OFF_VT + (dstage + 3) * 40 + jsw] = (_Float16)vx.w;
  }
#pragma unroll
  for (int p = 0; p < 3; ++p) {
    int ti = 2 * p + (t >> 7), row = (t >> 3) & 15, d4 = (t & 7) << 2;
    {
      int kL = 60 - i16 + ti;
      int tg = (kL << 4) + row; tg = tg < 0 ? 0 : (tg > S - 1 ? S - 1 : tg);
      float4 rv = *(const float4*)(r + (size_t)tg * HID + n * DH + d4);
      int sl = (kL + 72) & 7;
      cvtf16_4(rv, &sm[OFF_RL + (sl * 16 + row) * 40 + d4]);
    }
    if (proH) {
      int kH = -i16 - 3 + ti;
      int tg = (kH << 4) - 17 + row; tg = tg < 0 ? 0 : (tg > S - 1 ? S - 1 : tg);
      float4 rv = *(const float4*)(r + (size_t)tg * HID + n * DH + d4);
      int sl = (kH + 72) & 7;
      cvtf16_4(rv, &sm[OFF_RH + (sl * 16 + row) * 40 + d4]);
    }
  }

  for (int jt = 0; jt < 32; ++jt) {
    const int j0 = jt << 5;
    __syncthreads();

    const bool doKV = (jt < 31);
    const bool doRL = (jt <= jtL_last);
    const bool doRH = (32 * jt >= i0 - 125);
    float4 kx, vx, rlv, rhv;
    int slL = 0, slH = 0;
    {
      if (doKV) {
        const size_t g = (size_t)(j0 + 32 + jstage) * 2048 + b * HID + n * DH + dstage;
        kx = *(const float4*)(k + g);
        vx = *(const float4*)(v + g);
      }
      const int ti = t >> 7, row = (t >> 3) & 15, d4r = (t & 7) << 2;
      if (doRL) {
        int kL = 66 + 2 * jt - i16 + ti;
        int tg = (kL << 4) + row; tg = tg < 0 ? 0 : (tg > S - 1 ? S - 1 : tg);
        rlv = *(const float4*)(r + (size_t)tg * HID + n * DH + d4r);
        slL = (kL + 72) & 7;
      }
      if (doRH) {
        int kH = 2 * jt - i16 + 3 + ti;
        int tg = (kH << 4) - 17 + row; tg = tg < 0 ? 0 : (tg > S - 1 ? S - 1 : tg);
        rhv = *(const float4*)(r + (size_t)tg * HID + n * DH + d4r);
        slH = (kH + 72) & 7;
      }
    }

    const int buf = (jt & 1) * 1280;
    const bool lowA = (j0 <= iw0 + 15);
    const bool highA = (j0 + 29 >= iw0);

    f32x4 ac0 = {0.f, 0.f, 0.f, 0.f}, ac1 = {0.f, 0.f, 0.f, 0.f};
    {
      f16x8 b0 = *(const f16x8*)&sm[OFF_K + buf + jn * 40 + colq];
      f16x8 b1 = *(const f16x8*)&sm[OFF_K + buf + (16 + jn) * 40 + colq];
      ac0 = MFMAH(qu_h, b0, ac0); ac0 = MFMAH(qu_l, b0, ac0);
      ac1 = MFMAH(qu_h, b1, ac1); ac1 = MFMAH(qu_l, b1, ac1);
    }

    f32x4 zl0 = {0.f,0.f,0.f,0.f}, zl1 = {0.f,0.f,0.f,0.f}, zl2 = {0.f,0.f,0.f,0.f};
    f32x4 zh0 = {0.f,0.f,0.f,0.f}, zh1 = {0.f,0.f,0.f,0.f}, zh2 = {0.f,0.f,0.f,0.f};
    if (lowA) {
#pragma unroll
      for (int z = 0; z < 3; ++z) {
        int kL = 63 - i16 - w + 2 * jt + z;
        int sl = (kL + 72) & 7;
        f16x8 rr = *(const f16x8*)&sm[OFF_RL + (sl * 16 + jn) * 40 + colq];
        f32x4 acc = {0.f, 0.f, 0.f, 0.f};
        acc = MFMAH(qv_h, rr, acc); acc = MFMAH(qv_l, rr, acc);
        if (z == 0) zl0 = acc; else if (z == 1) zl1 = acc; else zl2 = acc;
      }
    }
    if (highA) {
#pragma unroll
      for (int z = 0; z < 3; ++z) {
        int kH = 2 * jt - i16 - w + z;
        int sl = (kH + 72) & 7;
        f16x8 rr = *(const f16x8*)&sm[OFF_RH + (sl * 16 + jn) * 40 + colq];
        f32x4 acc = {0.f, 0.f, 0.f, 0.f};
        acc = MFMAH(qn_h, rr, acc); acc = MFMAH(qn_l, rr, acc);
        if (z == 0) zh0 = acc; else if (z == 1) zh1 = acc; else zh2 = acc;
      }
    }

#pragma unroll
    for (int g = 0; g < 4; ++g) {
      const int qr = (quad << 2) + g;
      const int c0 = 15 - qr + jn;
      const int src = (lane & 48) | (c0 & 15);
      const bool pred = (jn >= 15 - qr);
      float lo0 = 0.f, lo1 = 0.f, hv0 = 0.f, hv1 = 0.f;
      if (lowA) {
        float vA = pred ? zl0[g] : zl1[g];
        float vB = pred ? zl1[g] : zl2[g];
        lo0 = __shfl(vA, src, 64);
        lo1 = __shfl(vB, src, 64);
      }
      if (highA) {
        float vA = pred ? zh0[g] : zh1[g];
        float vB = pred ? zh1[g] : zh2[g];
        hv0 = __shfl(vA, src, 64);
        hv1 = __shfl(vB, src, 64);
      }
      const int dj0 = j0 + jn - iw0 - qr;
#pragma unroll
      for (int f = 0; f < 2; ++f) {
        const int dj = dj0 + (f << 4);
        const float bd = (dj <= 0) ? (f ? lo1 : lo0) : ((dj == 1) ? 0.f : (f ? hv1 : hv0));
        const float acv = f ? ac1[g] : ac0[g];
        const float sc = acv + bd;
        const float e2 = __builtin_amdgcn_exp2f(sc);
        const float tq = __builtin_amdgcn_rcpf(e2 + 1.f);
        const float pw = __builtin_amdgcn_exp2f(fmaf(tq, C_PWB, C_PWA));
        sm[OFF_P + w * 640 + qr * 40 + (f << 4) + jn] = (_Float16)pw;
      }
    }

    {
      f16x8 pa = *(const f16x8*)&sm[OFF_P + w * 640 + jn * 40 + colq];
      f16x8 v0 = *(const f16x8*)&sm[OFF_VT + buf + jn * 40 + vcolsw];
      f16x8 v1 = *(const f16x8*)&sm[OFF_VT + buf + (16 + jn) * 40 + vcolsw];
      out0 = MFMAH(pa, v0, out0);
      out1 = MFMAH(pa, v1, out1);
      out_sum = MFMAH(pa, ones1, out_sum);
      *(f16x8*)swsp = pa;
      swsp += 32;
    }

    {
      if (doKV) {
        const int nbuf = ((jt + 1) & 1) * 1280;
        cvtf16_4(kx, &sm[OFF_K + nbuf + jstage * 40 + dstage]);
        sm[OFF_VT + nbuf + (dstage + 0) * 40 + jsw] = (_Float16)vx.x;
        sm[OFF_VT + nbuf + (dstage + 1) * 40 + jsw] = (_Float16)vx.y;
        sm[OFF_VT + nbuf + (dstage + 2) * 40 + jsw] = (_Float16)vx.z;
        sm[OFF_VT + nbuf + (dstage + 3) * 40 + jsw] = (_Float16)vx.w;
      }
      const int row = (t >> 3) & 15, d4r = (t & 7) << 2;
      if (doRL) cvtf16_4(rlv, &sm[OFF_RL + (slL * 16 + row) * 40 + d4r]);
      if (doRH) cvtf16_4(rhv, &sm[OFF_RH + (slH * 16 + row) * 40 + d4r]);
    }
  }

#pragma unroll
  for (int g = 0; g < 4; ++g) {
    const float inv = 1.0f / out_sum[g];
    const int qr = (quad << 2) + g;
    float* op = out + (size_t)(iw0 + qr) * 2048 + b * HID + n * DH;
    op[jn] = out0[g] * inv;
    op[16 + jn] = out1[g] * inv;
  }
}

__global__ __launch_bounds__(1024)
void relattn_probs_86028194939537(const __half* __restrict__ sws, const int* __restrict__ mask,
                                  float* __restrict__ probs) {
  __shared__ _Float16 ebuf[8][1032];
  __shared__ unsigned char mb[9224];
  __shared__ float psum[8][4];
  __shared__ float binv[8];
  const int t = threadIdx.x;
  const int i = blockIdx.x;
  const int tj = t & 255, bg = t >> 8;
  const int j4 = tj << 2;
  const int wl = (t >> 6) & 3;

  {
    const int4* m4 = (const int4*)(mask + (size_t)i * 8192);
#pragma unroll
    for (int u = 0; u < 2; ++u) {
      int idx = t + (u << 10);
      int4 mv = m4[idx];
      int jj = idx >> 1, b0 = (idx & 1) << 2;
      mb[jj * 9 + b0 + 0] = (unsigned char)(mv.x != 0);
      mb[jj * 9 + b0 + 1] = (unsigned char)(mv.y != 0);
      mb[jj * 9 + b0 + 2] = (unsigned char)(mv.z != 0);
      mb[jj * 9 + b0 + 3] = (unsigned char)(mv.w != 0);
    }
  }
  __syncthreads();

#pragma unroll
  for (int bb = 0; bb < 2; ++bb) {
    const int b = (bg << 1) + bb;
    float a0 = 1.f, a1 = 1.f, a2 = 1.f, a3 = 1.f;
#pragma unroll
    for (int n = 0; n < 8; ++n) {
      f16x4 pv = *(const f16x4*)(sws + (((size_t)i * 8 + b) * 8 + n) * 1024 + j4);
      a0 *= (float)pv.x; a1 *= (float)pv.y; a2 *= (float)pv.z; a3 *= (float)pv.w;
    }
    float e0 = mb[(j4 + 0) * 9 + b] ? 0.f
             : __builtin_amdgcn_exp2f(0.125f * __builtin_amdgcn_logf(a0));
    float e1 = mb[(j4 + 1) * 9 + b] ? 0.f
             : __builtin_amdgcn_exp2f(0.125f * __builtin_amdgcn_logf(a1));
    float e2 = mb[(j4 + 2) * 9 + b] ? 0.f
             : __builtin_amdgcn_exp2f(0.125f * __builtin_amdgcn_logf(a2));
    float e3 = mb[(j4 + 3) * 9 + b] ? 0.f
             : __builtin_amdgcn_exp2f(0.125f * __builtin_amdgcn_logf(a3));
    f16x4 ev;
    ev.x = (_Float16)e0; ev.y = (_Float16)e1; ev.z = (_Float16)e2; ev.w = (_Float16)e3;
    *(f16x4*)&ebuf[b][j4] = ev;
    float s = ((float)ev.x + (float)ev.y) + ((float)ev.z + (float)ev.w);
#pragma unroll
    for (int off = 32; off > 0; off >>= 1) s += __shfl_xor(s, off, 64);
    if ((t & 63) == 0) psum[b][wl] = s;
  }
  __syncthreads();
  if (t < 8) binv[t] = 1.0f / (psum[t][0] + psum[t][1] + psum[t][2] + psum[t][3]);
  __syncthreads();
#pragma unroll
  for (int u = 0; u < 2; ++u) {
    int f0 = (t << 2) + (u << 12);
    float4 o;
    o.x = (float)ebuf[(f0 + 0) & 7][(f0 + 0) >> 3] * binv[(f0 + 0) & 7];
    o.y = (float)ebuf[(f0 + 1) & 7][(f0 + 1) >> 3] * binv[(f0 + 1) & 7];
    o.z = (float)ebuf[(f0 + 2) & 7][(f0 + 2) >> 3] * binv[(f0 + 2) & 7];
    o.w = (float)ebuf[(f0 + 3) & 7][(f0 + 3) >> 3] * binv[(f0 + 3) & 7];
    *(float4*)(probs + (size_t)i * 8192 + f0) = o;
  }
}

// =================== fallback (R4, proven) ===================
#define TI 8
#define TJ 8
#define NTILE (S / TJ)
#define KSTR 288
#define KOFF 0
#define VOFF (TJ * KSTR)
#define BAND (2 * TJ * KSTR)
#define PROWS (TI + TJ - 1)
#define BSTR 292
#define BVR (BAND + PROWS * BSTR)
#define BUKo (BVR + PROWS * 8)
#define LDS_FL (BUKo + 64)

__global__ __launch_bounds__(256, 2)
void relattn_main_fb(const float* __restrict__ q, const float* __restrict__ k,
                     const float* __restrict__ v, const float* __restrict__ r,
                     const float* __restrict__ bias_u, const float* __restrict__ bias_v,
                     const int* __restrict__ mask, float* __restrict__ out,
                     float* __restrict__ probs_raw, float* __restrict__ ws_logits, int use_ws) {
  __shared__ float smf[LDS_FL];
  const int t = threadIdx.x;
  const int n = t & 7;
  const int il = (t >> 3) & 7;
  const int jp = t >> 6;
  const int bid = blockIdx.x;
  const int b = bid & 7;
  const int i0 = (bid >> 3) * TI;
  const int i = i0 + il;
  float qq[DH], qn[DH];
  {
    const float4* qr = (const float4*)(q + (i * B + b) * HID + n * DH);
#pragma unroll
    for (int dd = 0; dd < 8; ++dd) {
      float4 a = qr[dd];
      qq[4*dd+0] = a.x; qq[4*dd+1] = a.y; qq[4*dd+2] = a.z; qq[4*dd+3] = a.w;
    }
    if (i + 1 < S) {
      const float4* q2 = (const float4*)(q + ((i + 1) * B + b) * HID + n * DH);
#pragma unroll
      for (int dd = 0; dd < 8; ++dd) {
        float4 a = q2[dd];
        qn[4*dd+0] = a.x; qn[4*dd+1] = a.y; qn[4*dd+2] = a.z; qn[4*dd+3] = a.w;
      }
    } else {
#pragma unroll
      for (int d = 0; d < DH; ++d) qn[d] = 0.f;
    }
  }
  float oacc[DH];
#pragma unroll
  for (int d = 0; d < DH; ++d) oacc[d] = 0.f;
  float lsum = 0.f;
  for (int jt = 0; jt < NTILE; ++jt) {
    const int j0 = jt * TJ;
    const int Pstar = i0 + (TI - 1) - j0;
    const int lowBase = S - TI + j0 - i0;
    const int upBase = j0 - i0 - (TI + 1);
    __syncthreads();
    {
      int u = t;
      int row = u >> 6, c = u & 63;
      int gofs = ((j0 + row) * B + b) * HID + c * 4;
      int lofs = row * KSTR + (c >> 3) * 36 + (c & 7) * 4;
      *(float4*)(smf + KOFF + lofs) = *(const float4*)(k + gofs);
      *(float4*)(smf + VOFF + lofs) = *(const float4*)(v + gofs);
      u = t + 256; row = u >> 6; c = u & 63;
      gofs = ((j0 + row) * B + b) * HID + c * 4;
      lofs = row * KSTR + (c >> 3) * 36 + (c & 7) * 4;
      *(float4*)(smf + KOFF + lofs) = *(const float4*)(k + gofs);
      *(float4*)(smf + VOFF + lofs) = *(const float4*)(v + gofs);
    }
    for (int u = t; u < PROWS * 64; u += 256) {
      int prow = u >> 6, c = u & 63;
      int trow = (prow <= Pstar) ? (lowBase + prow) : (upBase + prow);
      float4 val = make_float4(0.f, 0.f, 0.f, 0.f);
      if ((unsigned)trow < (unsigned)S) val = *(const float4*)(r + trow * HID + c * 4);
      *(float4*)(smf + BAND + prow * BSTR + (c >> 3) * 36 + (c & 7) * 4) = val;
    }
    if (t < 64 + PROWS * 8) {
      const float4 *bb, *src;
      int slot;
      bool zero = false;
      if (t < 64) {
        int jl = t >> 3, nn = t & 7;
        bb = (const float4*)(bias_u + nn * DH);
        src = (const float4*)(k + ((j0 + jl) * B + b) * HID + nn * DH);
        slot = BUKo + jl * 8 + nn;
      } else {
        int u2 = t - 64;
        int prow = u2 >> 3, nn = u2 & 7;
        int trow = (prow <= Pstar) ? (lowBase + prow) : (upBase + prow);
        bb = (const float4*)(bias_v + nn * DH);
        if ((unsigned)trow < (unsigned)S) src = (const float4*)(r + trow * HID + nn * DH);
        else { src = bb; zero = true; }
        slot = BVR + prow * 8 + nn;
      }
      float a0 = 0.f, a1 = 0.f, a2 = 0.f, a3 = 0.f;
#pragma unroll
      for (int dd = 0; dd < 8; ++dd) {
        float4 x = bb[dd], y = src[dd];
        a0 = fmaf(x.x, y.x, a0); a1 = fmaf(x.y, y.y, a1);
        a2 = fmaf(x.z, y.z, a2); a3 = fmaf(x.w, y.w, a3);
      }
      smf[slot] = zero ? 0.f : ((a0 + a1) + (a2 + a3));
    }
    __syncthreads();
#pragma unroll
    for (int jj = 0; jj < 2; ++jj) {
      const int jl = jp * 2 + jj;
      const int jg = j0 + jl;
      const int p = jl + (TI - 1) - il;
      float a0 = 0.f, a1 = 0.f, a2 = 0.f, a3 = 0.f;
      const float4* kr = (const float4*)(smf + KOFF + jl * KSTR + n * 36);
#pragma unroll
      for (int dd = 0; dd < 8; ++dd) {
        float4 kv = kr[dd];
        a0 = fmaf(qq[4*dd+0], kv.x, a0); a1 = fmaf(qq[4*dd+1], kv.y, a1);
        a2 = fmaf(qq[4*dd+2], kv.z, a2); a3 = fmaf(qq[4*dd+3], kv.w, a3);
      }
      float ac = (a0 + a1) + (a2 + a3) + smf[BUKo + jl * 8 + n];
      float b0 = 0.f, b1 = 0.f, b2 = 0.f, b3 = 0.f;
      const float4* br = (const float4*)(smf + BAND + p * BSTR + n * 36);
      if (jg <= i) {
#pragma unroll
        for (int dd = 0; dd < 8; ++dd) {
          float4 bv4 = br[dd];
          b0 = fmaf(qq[4*dd+0], bv4.x, b0); b1 = fmaf(qq[4*dd+1], bv4.y, b1);
          b2 = fmaf(qq[4*dd+2], bv4.z, b2); b3 = fmaf(qq[4*dd+3], bv4.w, b3);
        }
      } else {
#pragma unroll
        for (int dd = 0; dd < 8; ++dd) {
          float4 bv4 = br[dd];
          b0 = fmaf(qn[4*dd+0], bv4.x, b0); b1 = fmaf(qn[4*dd+1], bv4.y, b1);
          b2 = fmaf(qn[4*dd+2], bv4.z, b2); b3 = fmaf(qn[4*dd+3], bv4.w, b3);
        }
      }
      float bd = (b0 + b1) + (b2 + b3) + smf[BVR + p * 8 + n];
      float sr = (ac + bd) * SCALEF;
      sr = fminf(fmaxf(sr, -15.f), 15.f);
      float e2 = __expf(2.f * sr);
      float scv = 10.f * (e2 - 1.f) / (e2 + 1.f);
      float ssum = scv;
      ssum += __shfl_xor(ssum, 1, 64);
      ssum += __shfl_xor(ssum, 2, 64);
      ssum += __shfl_xor(ssum, 4, 64);
      if (n == 0) {
        float logit = ssum * 0.125f;
        if (use_ws) {
          ws_logits[(i * B + b) * S + jg] = logit;
        } else {
          int gofs = (i * S + jg) * B + b;
          probs_raw[gofs] = (mask[gofs] != 0) ? -1e30f : logit;
        }
      }
      float pw = __expf(scv);
      lsum += pw;
      const float4* vr = (const float4*)(smf + VOFF + jl * KSTR + n * 36);
#pragma unroll
      for (int dd = 0; dd < 8; ++dd) {
        float4 vv = vr[dd];
        oacc[4*dd+0] = fmaf(pw, vv.x, oacc[4*dd+0]);
        oacc[4*dd+1] = fmaf(pw, vv.y, oacc[4*dd+1]);
        oacc[4*dd+2] = fmaf(pw, vv.z, oacc[4*dd+2]);
        oacc[4*dd+3] = fmaf(pw, vv.w, oacc[4*dd+3]);
      }
    }
  }
  __syncthreads();
  if (jp >= 2) {
    float* red = smf + (t - 128) * 33;
#pragma unroll
    for (int d = 0; d < DH; ++d) red[d] = oacc[d];
    red[DH] = lsum;
  }
  __syncthreads();
  if (jp < 2) {
    const float* red = smf + t * 33;
#pragma unroll
    for (int d = 0; d < DH; ++d) oacc[d] += red[d];
    lsum += red[DH];
  }
  __syncthreads();
  if (jp == 1) {
    float* red = smf + (t - 64) * 33;
#pragma unroll
    for (int d = 0; d < DH; ++d) red[d] = oacc[d];
    red[DH] = lsum;
  }
  __syncthreads();
  if (jp == 0) {
    const float* red = smf + t * 33;
#pragma unroll
    for (int d = 0; d < DH; ++d) oacc[d] += red[d];
    lsum += red[DH];
    float inv = 1.f / lsum;
    float4* orow = (float4*)(out + (i * B + b) * HID + n * DH);
#pragma unroll
    for (int dd = 0; dd < 8; ++dd) {
      float4 o4;
      o4.x = oacc[4*dd+0] * inv; o4.y = oacc[4*dd+1] * inv;
      o4.z = oacc[4*dd+2] * inv; o4.w = oacc[4*dd+3] * inv;
      orow[dd] = o4;
    }
  }
}

__global__ __launch_bounds__(256)
void relattn_norm_fb(float* __restrict__ probs, const float* __restrict__ ws_logits,
                     const int* __restrict__ mask, int use_ws) {
  const int t = threadIdx.x;
  const int bid = blockIdx.x;
  const int b = bid & 7;
  const int i = bid >> 3;
  float vals[4];
  float s = 0.f;
#pragma unroll
  for (int kk = 0; kk < 4; ++kk) {
    int j = t + 256 * kk;
    float lg;
    if (use_ws) {
      lg = ws_logits[(i * B + b) * S + j];
      if (mask[(i * S + j) * B + b] != 0) lg = -1e30f;
    } else {
      lg = probs[(i * S + j) * B + b];
    }
    vals[kk] = __expf(lg);
    s += vals[kk];
  }
#pragma unroll
  for (int off = 32; off > 0; off >>= 1) s += __shfl_down(s, off, 64);
  __shared__ float wsum[4];
  __shared__ float tot;
  if ((t & 63) == 0) wsum[t >> 6] = s;
  __syncthreads();
  if (t == 0) tot = wsum[0] + wsum[1] + wsum[2] + wsum[3];
  __syncthreads();
  float inv = 1.f / tot;
#pragma unroll
  for (int kk = 0; kk < 4; ++kk) {
    int j = t + 256 * kk;
    probs[(i * S + j) * B + b] = vals[kk] * inv;
  }
}

extern "C" void kernel_launch(void* const* d_in, const int* in_sizes, int n_in,
                              void* d_out, int out_size, void* d_ws, size_t ws_size,
                              hipStream_t stream) {
  const float* q  = (const float*)d_in[0];
  const float* k  = (const float*)d_in[1];
  const float* v  = (const float*)d_in[2];
  const float* r  = (const float*)d_in[3];
  const float* bu = (const float*)d_in[4];
  const float* bv = (const float*)d_in[5];
  const int* mask = (const int*)d_in[6];
  float* out = (float*)d_out;
  float* probs = out + S * B * HID;

  const size_t WS_SWS = (size_t)S * S * B * NH * sizeof(__half);  // 128 MiB
  const size_t WS_FUSED = WS_SWS + 8192;

  if (ws_size >= WS_FUSED) {
    __half* sws = (__half*)d_ws;
    int* ctrl = (int*)((char*)d_ws + WS_SWS);
    relattn_init_ctrl<<<dim3(2), dim3(1024), 0, stream>>>(ctrl);
    relattn_fused_86028194939537<<<dim3(1024), dim3(256), 0, stream>>>(
        q, k, v, r, bu, bv, mask, out, probs, sws, ctrl);
    relattn_cleanup_86028194939537<<<dim3(1024), dim3(256), 0, stream>>>(
        sws, mask, probs, ctrl);
  } else if (ws_size >= WS_SWS) {
    __half* sws = (__half*)d_ws;
    relattn_mfma_86028194939537<<<dim3(1024), dim3(256), 0, stream>>>(
        q, k, v, r, bu, bv, out, sws);
    relattn_probs_86028194939537<<<dim3(1024), dim3(1024), 0, stream>>>(sws, mask, probs);
  } else {
    float* wsl = (float*)d_ws;
    const int use_ws = (ws_size >= (size_t)S * S * B * sizeof(float)) ? 1 : 0;
    relattn_main_fb<<<dim3((S / TI) * B), dim3(256), 0, stream>>>(
        q, k, v, r, bu, bv, mask, out, probs, wsl, use_ws);
    relattn_norm_fb<<<dim3(S * B), dim3(256), 0, stream>>>(probs, wsl, mask, use_ws);
  }
}

// Round 12
// 246.639 us; speedup vs baseline: 1.6860x; 1.6860x over previous
//
#include <hip/hip_runtime.h>
#include <hip/hip_fp16.h>

#define S 1024
#define B 8
#define NH 8
#define DH 32
#define HID 256
#define SCALEF 0.17677669529663687f

typedef __attribute__((ext_vector_type(8))) _Float16 f16x8;
typedef __attribute__((ext_vector_type(4))) _Float16 f16x4;
typedef __attribute__((ext_vector_type(4))) float f32x4;
#define MFMAH(a, b, c) __builtin_amdgcn_mfma_f32_16x16x32_f16(a, b, c, 0, 0, 0)

// ---- LDS layout (halfs), 17920 halfs = 35 KB (single-f16 K, dbuf) ----
#define OFF_K   0        // 2 buf x 32 x 40 (f16 K, single precision term)
#define OFF_VT  2560     // 2 buf x 32(d) x 40, col-XOR-swizzled
#define OFF_RL  5120     // ring 8 slots x 16 x 40
#define OFF_RH  10240
#define OFF_P   15360    // 4 waves x 16 x 40
#define LDS_HF  17920

// exp2-folded constants (C_E2 folded into q-fragments at build):
//   e2 = exp(2*sr) = exp2(s'),  s' = (AC+BD) pre-scaled by 2*SCALE/ln2
//   pw = exp(10*tanh(sr)) = exp2(14.4269504 - 28.8539008/(e2+1))
#define C_E2  0.51006978f      // 2*SCALE/ln2
#define C_PWA 14.42695041f     // 10/ln2
#define C_PWB -28.85390082f    // -20/ln2

__device__ __forceinline__ void cvtf16_4(const float4 x, _Float16* d) {
  f16x4 h;
  h.x = (_Float16)x.x; h.y = (_Float16)x.y; h.z = (_Float16)x.z; h.w = (_Float16)x.w;
  *(f16x4*)d = h;
}

// =================== fast path: MFMA kernel (R9-proven, 132 us) ===================
// sws stores pw = exp(10*tanh(sr)) as half, layout [i][b][n][j].
// dbuf, 1 barrier/jt, T14 split, ones-MFMA rowsum, single-f16 K, pa-reused sws dump.
__global__ __launch_bounds__(256)
void relattn_mfma_86028194939537(const float* __restrict__ q, const float* __restrict__ k,
                                 const float* __restrict__ v, const float* __restrict__ r,
                                 const float* __restrict__ bu, const float* __restrict__ bv,
                                 float* __restrict__ out, __half* __restrict__ sws) {
  __shared__ _Float16 sm[LDS_HF];
  const int t = threadIdx.x;
  const int lane = t & 63, w = t >> 6;
  const int quad = lane >> 4, jn = lane & 15;
  const int bid = blockIdx.x;
  const int b = bid & 7, it = (bid >> 3) & 15, n = bid >> 7;
  const int i0 = it << 6, iw0 = i0 + (w << 4);
  const int colq = quad << 3;
  const int i16 = i0 >> 4;

  // staging thread mapping (hoisted) + V col-swizzle: col j stored at j ^ ((d>>2)&3)<<3
  const int jstage = t >> 3, dstage = (t & 7) << 2;
  const int jsw = jstage ^ ((t & 3) << 3);          // (dstage>>2)&3 == t&3
  // V read col swizzle: row d = jn (v0) or 16+jn (v1) -> same s = (jn>>2)&3
  const int vcolsw = colq ^ (((jn >> 2) & 3) << 3); // loop-invariant

  // r-staging liveness gates (block-uniform)
  const int jtL_last = (i0 + 63) >> 5;   // RL consumed only while jt <= this
  const bool proH = (i0 <= 125);         // RH prologue needed only for small i0

  // ---- A-frags (f16 hi/lo), pre-scaled by C_E2: qu=(q+bu)*c, qv=(q+bv)*c, qn=(q[+1]+bv)*c ----
  f16x8 qu_h, qu_l, qv_h, qv_l, qn_h, qn_l;
  {
    const float* bup = bu + n * DH + colq;
    const float* bvp = bv + n * DH + colq;
    const float* qp = q + (size_t)(iw0 + jn) * 2048 + b * HID + n * DH + colq;
    int r1 = iw0 + 1 + jn; if (r1 > S - 1) r1 = S - 1;
    const float* qp1 = q + (size_t)r1 * 2048 + b * HID + n * DH + colq;
#pragma unroll
    for (int e = 0; e < 8; ++e) {
      float xu = (qp[e] + bup[e]) * C_E2;
      float xv = (qp[e] + bvp[e]) * C_E2;
      float xn = (qp1[e] + bvp[e]) * C_E2;
      _Float16 h;
      h = (_Float16)xu; qu_h[e] = h; qu_l[e] = (_Float16)(xu - (float)h);
      h = (_Float16)xv; qv_h[e] = h; qv_l[e] = (_Float16)(xv - (float)h);
      h = (_Float16)xn; qn_h[e] = h; qn_l[e] = (_Float16)(xn - (float)h);
    }
  }

  // all-ones B fragment for the rowsum MFMA
  f16x8 ones1;
#pragma unroll
  for (int e = 0; e < 8; ++e) ones1[e] = (_Float16)1.0f;

  // sws dump reuses pa (PV A-frag): lane l holds P[row=l&15][cols (l>>4)*8..+8];
  // store lands at row iw0+jn, j-cols j0+colq..+8 (fully coalesced across lanes).
  __half* swsp = sws + (((size_t)(iw0 + jn) * 8 + b) * 8 + n) * 1024 + colq;

  f32x4 out0 = {0.f, 0.f, 0.f, 0.f}, out1 = {0.f, 0.f, 0.f, 0.f};
  f32x4 out_sum = {0.f, 0.f, 0.f, 0.f};

  // ---- prologue: K/V buf0 (jt=0) + 6 r tiles per family ----
  {
    const size_t g = (size_t)jstage * 2048 + b * HID + n * DH + dstage;
    float4 kx = *(const float4*)(k + g);
    float4 vx = *(const float4*)(v + g);
    cvtf16_4(kx, &sm[OFF_K + jstage * 40 + dstage]);
    sm[OFF_VT + (dstage + 0) * 40 + jsw] = (_Float16)vx.x;
    sm[OFF_VT + (dstage + 1) * 40 + jsw] = (_Float16)vx.y;
    sm[OFF_VT + (dstage + 2) * 40 + jsw] = (_Float16)vx.z;
    sm[OFF_VT + (dstage + 3) * 40 + jsw] = (_Float16)vx.w;
  }
#pragma unroll
  for (int p = 0; p < 3; ++p) {
    int ti = 2 * p + (t >> 7), row = (t >> 3) & 15, d4 = (t & 7) << 2;
    {
      int kL = 60 - i16 + ti;
      int tg = (kL << 4) + row; tg = tg < 0 ? 0 : (tg > S - 1 ? S - 1 : tg);
      float4 rv = *(const float4*)(r + (size_t)tg * HID + n * DH + d4);
      int sl = (kL + 72) & 7;
      cvtf16_4(rv, &sm[OFF_RL + (sl * 16 + row) * 40 + d4]);
    }
    if (proH) {
      int kH = -i16 - 3 + ti;
      int tg = (kH << 4) - 17 + row; tg = tg < 0 ? 0 : (tg > S - 1 ? S - 1 : tg);
      float4 rv = *(const float4*)(r + (size_t)tg * HID + n * DH + d4);
      int sl = (kH + 72) & 7;
      cvtf16_4(rv, &sm[OFF_RH + (sl * 16 + row) * 40 + d4]);
    }
  }

  for (int jt = 0; jt < 32; ++jt) {
    const int j0 = jt << 5;
    __syncthreads();   // the ONLY barrier per jt

    // ---- phase 1: ISSUE next-tile global loads into registers (T14 split) ----
    const bool doKV = (jt < 31);
    const bool doRL = (jt <= jtL_last);
    const bool doRH = (32 * jt >= i0 - 125);
    float4 kx, vx, rlv, rhv;
    int slL = 0, slH = 0;
    {
      if (doKV) {
        const size_t g = (size_t)(j0 + 32 + jstage) * 2048 + b * HID + n * DH + dstage;
        kx = *(const float4*)(k + g);
        vx = *(const float4*)(v + g);
      }
      const int ti = t >> 7, row = (t >> 3) & 15, d4r = (t & 7) << 2;
      if (doRL) {
        int kL = 66 + 2 * jt - i16 + ti;
        int tg = (kL << 4) + row; tg = tg < 0 ? 0 : (tg > S - 1 ? S - 1 : tg);
        rlv = *(const float4*)(r + (size_t)tg * HID + n * DH + d4r);
        slL = (kL + 72) & 7;
      }
      if (doRH) {
        int kH = 2 * jt - i16 + 3 + ti;
        int tg = (kH << 4) - 17 + row; tg = tg < 0 ? 0 : (tg > S - 1 ? S - 1 : tg);
        rhv = *(const float4*)(r + (size_t)tg * HID + n * DH + d4r);
        slH = (kH + 72) & 7;
      }
    }

    const int buf = (jt & 1) * 1280;
    const bool lowA = (j0 <= iw0 + 15);
    const bool highA = (j0 + 29 >= iw0);

    // ---- phase 2: compute from buf staged during jt-1 ----
    // AC = (q+bu) . k^T : 2 N-tiles, single-f16 K x hi/lo q (2 MFMA per tile)
    f32x4 ac0 = {0.f, 0.f, 0.f, 0.f}, ac1 = {0.f, 0.f, 0.f, 0.f};
    {
      f16x8 b0 = *(const f16x8*)&sm[OFF_K + buf + jn * 40 + colq];
      f16x8 b1 = *(const f16x8*)&sm[OFF_K + buf + (16 + jn) * 40 + colq];
      ac0 = MFMAH(qu_h, b0, ac0); ac0 = MFMAH(qu_l, b0, ac0);
      ac1 = MFMAH(qu_h, b1, ac1); ac1 = MFMAH(qu_l, b1, ac1);
    }

    // Z bands (single-f16 r: 2 MFMA per tile)
    f32x4 zl0 = {0.f,0.f,0.f,0.f}, zl1 = {0.f,0.f,0.f,0.f}, zl2 = {0.f,0.f,0.f,0.f};
    f32x4 zh0 = {0.f,0.f,0.f,0.f}, zh1 = {0.f,0.f,0.f,0.f}, zh2 = {0.f,0.f,0.f,0.f};
    if (lowA) {
#pragma unroll
      for (int z = 0; z < 3; ++z) {
        int kL = 63 - i16 - w + 2 * jt + z;
        int sl = (kL + 72) & 7;
        f16x8 rr = *(const f16x8*)&sm[OFF_RL + (sl * 16 + jn) * 40 + colq];
        f32x4 acc = {0.f, 0.f, 0.f, 0.f};
        acc = MFMAH(qv_h, rr, acc); acc = MFMAH(qv_l, rr, acc);
        if (z == 0) zl0 = acc; else if (z == 1) zl1 = acc; else zl2 = acc;
      }
    }
    if (highA) {
#pragma unroll
      for (int z = 0; z < 3; ++z) {
        int kH = 2 * jt - i16 - w + z;
        int sl = (kH + 72) & 7;
        f16x8 rr = *(const f16x8*)&sm[OFF_RH + (sl * 16 + jn) * 40 + colq];
        f32x4 acc = {0.f, 0.f, 0.f, 0.f};
        acc = MFMAH(qn_h, rr, acc); acc = MFMAH(qn_l, rr, acc);
        if (z == 0) zh0 = acc; else if (z == 1) zh1 = acc; else zh2 = acc;
      }
    }

    // gather + score + P (select-before-shfl: 2 bpermute per family)
#pragma unroll
    for (int g = 0; g < 4; ++g) {
      const int qr = (quad << 2) + g;
      const int c0 = 15 - qr + jn;
      const int src = (lane & 48) | (c0 & 15);
      // source-side predicate == reader's zs (quad-preserving shuffle, same qr)
      const bool pred = (jn >= 15 - qr);
      float lo0 = 0.f, lo1 = 0.f, hv0 = 0.f, hv1 = 0.f;
      if (lowA) {
        float vA = pred ? zl0[g] : zl1[g];
        float vB = pred ? zl1[g] : zl2[g];
        lo0 = __shfl(vA, src, 64);
        lo1 = __shfl(vB, src, 64);
      }
      if (highA) {
        float vA = pred ? zh0[g] : zh1[g];
        float vB = pred ? zh1[g] : zh2[g];
        hv0 = __shfl(vA, src, 64);
        hv1 = __shfl(vB, src, 64);
      }
      const int dj0 = j0 + jn - iw0 - qr;
#pragma unroll
      for (int f = 0; f < 2; ++f) {
        const int dj = dj0 + (f << 4);
        const float bd = (dj <= 0) ? (f ? lo1 : lo0) : ((dj == 1) ? 0.f : (f ? hv1 : hv0));
        const float acv = f ? ac1[g] : ac0[g];
        const float s = acv + bd;                       // already * C_E2
        const float e2 = __builtin_amdgcn_exp2f(s);
        const float tq = __builtin_amdgcn_rcpf(e2 + 1.f);
        const float pw = __builtin_amdgcn_exp2f(fmaf(tq, C_PWB, C_PWA));
        sm[OFF_P + w * 640 + qr * 40 + (f << 4) + jn] = (_Float16)pw;
      }
    }

    // PV: out += P(f16).V^T(f16); out_sum += P.ones (rowsum on the MFMA pipe);
    // sws dump reuses pa (no extra LDS read).
    {
      f16x8 pa = *(const f16x8*)&sm[OFF_P + w * 640 + jn * 40 + colq];
      f16x8 v0 = *(const f16x8*)&sm[OFF_VT + buf + jn * 40 + vcolsw];
      f16x8 v1 = *(const f16x8*)&sm[OFF_VT + buf + (16 + jn) * 40 + vcolsw];
      out0 = MFMAH(pa, v0, out0);
      out1 = MFMAH(pa, v1, out1);
      out_sum = MFMAH(pa, ones1, out_sum);
      *(f16x8*)swsp = pa;
      swsp += 32;
    }

    // ---- phase 3: convert + LDS writes (loads had the whole compute to land) ----
    {
      if (doKV) {
        const int nbuf = ((jt + 1) & 1) * 1280;
        cvtf16_4(kx, &sm[OFF_K + nbuf + jstage * 40 + dstage]);
        sm[OFF_VT + nbuf + (dstage + 0) * 40 + jsw] = (_Float16)vx.x;
        sm[OFF_VT + nbuf + (dstage + 1) * 40 + jsw] = (_Float16)vx.y;
        sm[OFF_VT + nbuf + (dstage + 2) * 40 + jsw] = (_Float16)vx.z;
        sm[OFF_VT + nbuf + (dstage + 3) * 40 + jsw] = (_Float16)vx.w;
      }
      const int row = (t >> 3) & 15, d4r = (t & 7) << 2;
      if (doRL) cvtf16_4(rlv, &sm[OFF_RL + (slL * 16 + row) * 40 + d4r]);
      if (doRH) cvtf16_4(rhv, &sm[OFF_RH + (slH * 16 + row) * 40 + d4r]);
    }
  }

  // ---- epilogue: rowsum is in out_sum (all cols identical) — no reduce needed ----
#pragma unroll
  for (int g = 0; g < 4; ++g) {
    const float inv = 1.0f / out_sum[g];
    const int qr = (quad << 2) + g;
    float* op = out + (size_t)(iw0 + qr) * 2048 + b * HID + n * DH;
    op[jn] = out0[g] * inv;
    op[16 + jn] = out1[g] * inv;
  }
}

// =================== fast path: probs kernel v7 (1024 threads, 16 waves) ===================
// pad-9 mb; exp2(log/8) root; no cross-bb prefetch (64-VGPR occupancy cliff).
__global__ __launch_bounds__(1024)
void relattn_probs_86028194939537(const __half* __restrict__ sws, const int* __restrict__ mask,
                                  float* __restrict__ probs) {
  __shared__ _Float16 ebuf[8][1032];     // 16.1 KB
  __shared__ unsigned char mb[9224];     // [j*9 + b] pad-9: conflict-free reads
  __shared__ float psum[8][4];
  __shared__ float binv[8];
  const int t = threadIdx.x;
  const int i = blockIdx.x;
  const int tj = t & 255, bg = t >> 8;   // bg in 0..3 -> b = 2bg, 2bg+1
  const int j4 = tj << 2;
  const int wl = (t >> 6) & 3;           // wave-within-b-group

  // stage mask: int[j][b] -> byte mb[j*9+b]
  {
    const int4* m4 = (const int4*)(mask + (size_t)i * 8192);
#pragma unroll
    for (int u = 0; u < 2; ++u) {
      int idx = t + (u << 10);           // int-quad index; ints m = 4*idx..+3
      int4 mv = m4[idx];
      int jj = idx >> 1, b0 = (idx & 1) << 2;
      mb[jj * 9 + b0 + 0] = (unsigned char)(mv.x != 0);
      mb[jj * 9 + b0 + 1] = (unsigned char)(mv.y != 0);
      mb[jj * 9 + b0 + 2] = (unsigned char)(mv.z != 0);
      mb[jj * 9 + b0 + 3] = (unsigned char)(mv.w != 0);
    }
  }
  __syncthreads();

#pragma unroll
  for (int bb = 0; bb < 2; ++bb) {
    const int b = (bg << 1) + bb;
    float a0 = 1.f, a1 = 1.f, a2 = 1.f, a3 = 1.f;
#pragma unroll
    for (int n = 0; n < 8; ++n) {
      f16x4 pv = *(const f16x4*)(sws + (((size_t)i * 8 + b) * 8 + n) * 1024 + j4);
      a0 *= (float)pv.x; a1 *= (float)pv.y; a2 *= (float)pv.z; a3 *= (float)pv.w;
    }
    // e = a^(1/8) = exp2(log2(a)/8); a in [e^-80, e^80] -> log2 in [-115.4, 115.4]
    float e0 = mb[(j4 + 0) * 9 + b] ? 0.f
             : __builtin_amdgcn_exp2f(0.125f * __builtin_amdgcn_logf(a0));
    float e1 = mb[(j4 + 1) * 9 + b] ? 0.f
             : __builtin_amdgcn_exp2f(0.125f * __builtin_amdgcn_logf(a1));
    float e2 = mb[(j4 + 2) * 9 + b] ? 0.f
             : __builtin_amdgcn_exp2f(0.125f * __builtin_amdgcn_logf(a2));
    float e3 = mb[(j4 + 3) * 9 + b] ? 0.f
             : __builtin_amdgcn_exp2f(0.125f * __builtin_amdgcn_logf(a3));
    f16x4 ev;
    ev.x = (_Float16)e0; ev.y = (_Float16)e1; ev.z = (_Float16)e2; ev.w = (_Float16)e3;
    *(f16x4*)&ebuf[b][j4] = ev;
    float s = ((float)ev.x + (float)ev.y) + ((float)ev.z + (float)ev.w);
#pragma unroll
    for (int off = 32; off > 0; off >>= 1) s += __shfl_xor(s, off, 64);
    if ((t & 63) == 0) psum[b][wl] = s;
  }
  __syncthreads();
  if (t < 8) binv[t] = 1.0f / (psum[t][0] + psum[t][1] + psum[t][2] + psum[t][3]);
  __syncthreads();
  // coalesced float4 writes of all 8192 (j,b) values (2 per thread)
#pragma unroll
  for (int u = 0; u < 2; ++u) {
    int f0 = (t << 2) + (u << 12);
    float4 o;
    o.x = (float)ebuf[(f0 + 0) & 7][(f0 + 0) >> 3] * binv[(f0 + 0) & 7];
    o.y = (float)ebuf[(f0 + 1) & 7][(f0 + 1) >> 3] * binv[(f0 + 1) & 7];
    o.z = (float)ebuf[(f0 + 2) & 7][(f0 + 2) >> 3] * binv[(f0 + 2) & 7];
    o.w = (float)ebuf[(f0 + 3) & 7][(f0 + 3) >> 3] * binv[(f0 + 3) & 7];
    *(float4*)(probs + (size_t)i * 8192 + f0) = o;
  }
}

// =================== fallback (R4, proven) ===================
#define TI 8
#define TJ 8
#define NTILE (S / TJ)
#define KSTR 288
#define KOFF 0
#define VOFF (TJ * KSTR)
#define BAND (2 * TJ * KSTR)
#define PROWS (TI + TJ - 1)
#define BSTR 292
#define BVR (BAND + PROWS * BSTR)
#define BUKo (BVR + PROWS * 8)
#define LDS_FL (BUKo + 64)

__global__ __launch_bounds__(256, 2)
void relattn_main_fb(const float* __restrict__ q, const float* __restrict__ k,
                     const float* __restrict__ v, const float* __restrict__ r,
                     const float* __restrict__ bias_u, const float* __restrict__ bias_v,
                     const int* __restrict__ mask, float* __restrict__ out,
                     float* __restrict__ probs_raw, float* __restrict__ ws_logits, int use_ws) {
  __shared__ float smf[LDS_FL];
  const int t = threadIdx.x;
  const int n = t & 7;
  const int il = (t >> 3) & 7;
  const int jp = t >> 6;
  const int bid = blockIdx.x;
  const int b = bid & 7;
  const int i0 = (bid >> 3) * TI;
  const int i = i0 + il;
  float qq[DH], qn[DH];
  {
    const float4* qr = (const float4*)(q + (i * B + b) * HID + n * DH);
#pragma unroll
    for (int dd = 0; dd < 8; ++dd) {
      float4 a = qr[dd];
      qq[4*dd+0] = a.x; qq[4*dd+1] = a.y; qq[4*dd+2] = a.z; qq[4*dd+3] = a.w;
    }
    if (i + 1 < S) {
      const float4* q2 = (const float4*)(q + ((i + 1) * B + b) * HID + n * DH);
#pragma unroll
      for (int dd = 0; dd < 8; ++dd) {
        float4 a = q2[dd];
        qn[4*dd+0] = a.x; qn[4*dd+1] = a.y; qn[4*dd+2] = a.z; qn[4*dd+3] = a.w;
      }
    } else {
#pragma unroll
      for (int d = 0; d < DH; ++d) qn[d] = 0.f;
    }
  }
  float oacc[DH];
#pragma unroll
  for (int d = 0; d < DH; ++d) oacc[d] = 0.f;
  float lsum = 0.f;
  for (int jt = 0; jt < NTILE; ++jt) {
    const int j0 = jt * TJ;
    const int Pstar = i0 + (TI - 1) - j0;
    const int lowBase = S - TI + j0 - i0;
    const int upBase = j0 - i0 - (TI + 1);
    __syncthreads();
    {
      int u = t;
      int row = u >> 6, c = u & 63;
      int gofs = ((j0 + row) * B + b) * HID + c * 4;
      int lofs = row * KSTR + (c >> 3) * 36 + (c & 7) * 4;
      *(float4*)(smf + KOFF + lofs) = *(const float4*)(k + gofs);
      *(float4*)(smf + VOFF + lofs) = *(const float4*)(v + gofs);
      u = t + 256; row = u >> 6; c = u & 63;
      gofs = ((j0 + row) * B + b) * HID + c * 4;
      lofs = row * KSTR + (c >> 3) * 36 + (c & 7) * 4;
      *(float4*)(smf + KOFF + lofs) = *(const float4*)(k + gofs);
      *(float4*)(smf + VOFF + lofs) = *(const float4*)(v + gofs);
    }
    for (int u = t; u < PROWS * 64; u += 256) {
      int prow = u >> 6, c = u & 63;
      int trow = (prow <= Pstar) ? (lowBase + prow) : (upBase + prow);
      float4 val = make_float4(0.f, 0.f, 0.f, 0.f);
      if ((unsigned)trow < (unsigned)S) val = *(const float4*)(r + trow * HID + c * 4);
      *(float4*)(smf + BAND + prow * BSTR + (c >> 3) * 36 + (c & 7) * 4) = val;
    }
    if (t < 64 + PROWS * 8) {
      const float4 *bb, *src;
      int slot;
      bool zero = false;
      if (t < 64) {
        int jl = t >> 3, nn = t & 7;
        bb = (const float4*)(bias_u + nn * DH);
        src = (const float4*)(k + ((j0 + jl) * B + b) * HID + nn * DH);
        slot = BUKo + jl * 8 + nn;
      } else {
        int u2 = t - 64;
        int prow = u2 >> 3, nn = u2 & 7;
        int trow = (prow <= Pstar) ? (lowBase + prow) : (upBase + prow);
        bb = (const float4*)(bias_v + nn * DH);
        if ((unsigned)trow < (unsigned)S) src = (const float4*)(r + trow * HID + nn * DH);
        else { src = bb; zero = true; }
        slot = BVR + prow * 8 + nn;
      }
      float a0 = 0.f, a1 = 0.f, a2 = 0.f, a3 = 0.f;
#pragma unroll
      for (int dd = 0; dd < 8; ++dd) {
        float4 x = bb[dd], y = src[dd];
        a0 = fmaf(x.x, y.x, a0); a1 = fmaf(x.y, y.y, a1);
        a2 = fmaf(x.z, y.z, a2); a3 = fmaf(x.w, y.w, a3);
      }
      smf[slot] = zero ? 0.f : ((a0 + a1) + (a2 + a3));
    }
    __syncthreads();
#pragma unroll
    for (int jj = 0; jj < 2; ++jj) {
      const int jl = jp * 2 + jj;
      const int jg = j0 + jl;
      const int p = jl + (TI - 1) - il;
      float a0 = 0.f, a1 = 0.f, a2 = 0.f, a3 = 0.f;
      const float4* kr = (const float4*)(smf + KOFF + jl * KSTR + n * 36);
#pragma unroll
      for (int dd = 0; dd < 8; ++dd) {
        float4 kv = kr[dd];
        a0 = fmaf(qq[4*dd+0], kv.x, a0); a1 = fmaf(qq[4*dd+1], kv.y, a1);
        a2 = fmaf(qq[4*dd+2], kv.z, a2); a3 = fmaf(qq[4*dd+3], kv.w, a3);
      }
      float ac = (a0 + a1) + (a2 + a3) + smf[BUKo + jl * 8 + n];
      float b0 = 0.f, b1 = 0.f, b2 = 0.f, b3 = 0.f;
      const float4* br = (const float4*)(smf + BAND + p * BSTR + n * 36);
      if (jg <= i) {
#pragma unroll
        for (int dd = 0; dd < 8; ++dd) {
          float4 bv4 = br[dd];
          b0 = fmaf(qq[4*dd+0], bv4.x, b0); b1 = fmaf(qq[4*dd+1], bv4.y, b1);
          b2 = fmaf(qq[4*dd+2], bv4.z, b2); b3 = fmaf(qq[4*dd+3], bv4.w, b3);
        }
      } else {
#pragma unroll
        for (int dd = 0; dd < 8; ++dd) {
          float4 bv4 = br[dd];
          b0 = fmaf(qn[4*dd+0], bv4.x, b0); b1 = fmaf(qn[4*dd+1], bv4.y, b1);
          b2 = fmaf(qn[4*dd+2], bv4.z, b2); b3 = fmaf(qn[4*dd+3], bv4.w, b3);
        }
      }
      float bd = (b0 + b1) + (b2 + b3) + smf[BVR + p * 8 + n];
      float sr = (ac + bd) * SCALEF;
      sr = fminf(fmaxf(sr, -15.f), 15.f);
      float e2 = __expf(2.f * sr);
      float scv = 10.f * (e2 - 1.f) / (e2 + 1.f);
      float ssum = scv;
      ssum += __shfl_xor(ssum, 1, 64);
      ssum += __shfl_xor(ssum, 2, 64);
      ssum += __shfl_xor(ssum, 4, 64);
      if (n == 0) {
        float logit = ssum * 0.125f;
        if (use_ws) {
          ws_logits[(i * B + b) * S + jg] = logit;
        } else {
          int gofs = (i * S + jg) * B + b;
          probs_raw[gofs] = (mask[gofs] != 0) ? -1e30f : logit;
        }
      }
      float pw = __expf(scv);
      lsum += pw;
      const float4* vr = (const float4*)(smf + VOFF + jl * KSTR + n * 36);
#pragma unroll
      for (int dd = 0; dd < 8; ++dd) {
        float4 vv = vr[dd];
        oacc[4*dd+0] = fmaf(pw, vv.x, oacc[4*dd+0]);
        oacc[4*dd+1] = fmaf(pw, vv.y, oacc[4*dd+1]);
        oacc[4*dd+2] = fmaf(pw, vv.z, oacc[4*dd+2]);
        oacc[4*dd+3] = fmaf(pw, vv.w, oacc[4*dd+3]);
      }
    }
  }
  __syncthreads();
  if (jp >= 2) {
    float* red = smf + (t - 128) * 33;
#pragma unroll
    for (int d = 0; d < DH; ++d) red[d] = oacc[d];
    red[DH] = lsum;
  }
  __syncthreads();
  if (jp < 2) {
    const float* red = smf + t * 33;
#pragma unroll
    for (int d = 0; d < DH; ++d) oacc[d] += red[d];
    lsum += red[DH];
  }
  __syncthreads();
  if (jp == 1) {
    float* red = smf + (t - 64) * 33;
#pragma unroll
    for (int d = 0; d < DH; ++d) red[d] = oacc[d];
    red[DH] = lsum;
  }
  __syncthreads();
  if (jp == 0) {
    const float* red = smf + t * 33;
#pragma unroll
    for (int d = 0; d < DH; ++d) oacc[d] += red[d];
    lsum += red[DH];
    float inv = 1.f / lsum;
    float4* orow = (float4*)(out + (i * B + b) * HID + n * DH);
#pragma unroll
    for (int dd = 0; dd < 8; ++dd) {
      float4 o4;
      o4.x = oacc[4*dd+0] * inv; o4.y = oacc[4*dd+1] * inv;
      o4.z = oacc[4*dd+2] * inv; o4.w = oacc[4*dd+3] * inv;
      orow[dd] = o4;
    }
  }
}

__global__ __launch_bounds__(256)
void relattn_norm_fb(float* __restrict__ probs, const float* __restrict__ ws_logits,
                     const int* __restrict__ mask, int use_ws) {
  const int t = threadIdx.x;
  const int bid = blockIdx.x;
  const int b = bid & 7;
  const int i = bid >> 3;
  float vals[4];
  float s = 0.f;
#pragma unroll
  for (int kk = 0; kk < 4; ++kk) {
    int j = t + 256 * kk;
    float lg;
    if (use_ws) {
      lg = ws_logits[(i * B + b) * S + j];
      if (mask[(i * S + j) * B + b] != 0) lg = -1e30f;
    } else {
      lg = probs[(i * S + j) * B + b];
    }
    vals[kk] = __expf(lg);
    s += vals[kk];
  }
#pragma unroll
  for (int off = 32; off > 0; off >>= 1) s += __shfl_down(s, off, 64);
  __shared__ float wsum[4];
  __shared__ float tot;
  if ((t & 63) == 0) wsum[t >> 6] = s;
  __syncthreads();
  if (t == 0) tot = wsum[0] + wsum[1] + wsum[2] + wsum[3];
  __syncthreads();
  float inv = 1.f / tot;
#pragma unroll
  for (int kk = 0; kk < 4; ++kk) {
    int j = t + 256 * kk;
    probs[(i * S + j) * B + b] = vals[kk] * inv;
  }
}

extern "C" void kernel_launch(void* const* d_in, const int* in_sizes, int n_in,
                              void* d_out, int out_size, void* d_ws, size_t ws_size,
                              hipStream_t stream) {
  const float* q  = (const float*)d_in[0];
  const float* k  = (const float*)d_in[1];
  const float* v  = (const float*)d_in[2];
  const float* r  = (const float*)d_in[3];
  const float* bu = (const float*)d_in[4];
  const float* bv = (const float*)d_in[5];
  const int* mask = (const int*)d_in[6];
  float* out = (float*)d_out;
  float* probs = out + S * B * HID;

  const size_t WS_NEED = (size_t)S * S * B * NH * sizeof(__half);  // 128 MiB
  if (ws_size >= WS_NEED) {
    __half* sws = (__half*)d_ws;
    relattn_mfma_86028194939537<<<dim3(1024), dim3(256), 0, stream>>>(
        q, k, v, r, bu, bv, out, sws);
    relattn_probs_86028194939537<<<dim3(1024), dim3(1024), 0, stream>>>(sws, mask, probs);
  } else {
    float* wsl = (float*)d_ws;
    const int use_ws = (ws_size >= (size_t)S * S * B * sizeof(float)) ? 1 : 0;
    relattn_main_fb<<<dim3((S / TI) * B), dim3(256), 0, stream>>>(
        q, k, v, r, bu, bv, mask, out, probs, wsl, use_ws);
    relattn_norm_fb<<<dim3(S * B), dim3(256), 0, stream>>>(probs, wsl, mask, use_ws);
  }
}